// Round 2
// baseline (397.200 us; speedup 1.0000x reference)
//
#include <hip/hip_runtime.h>
#include <cstdint>
#include <cstddef>

#define EPSF 1e-5f
#define LEAKF 0.01f
#define AVGD 3.3f

static constexpr int Bn  = 8, Nn = 256, DIN = 128, DE = 64, Hn = 128;
static constexpr int BN  = Bn * Nn;        // 2048 nodes
static constexpr int MEXT = 12 * DIN;      // 1536
static constexpr int CT  = DIN + MEXT;     // 1664 = post_W rows

__device__ __forceinline__ float bf2f(uint16_t u) { return __uint_as_float(((uint32_t)u) << 16); }
__device__ __forceinline__ float bflo(uint32_t u)  { return __uint_as_float(u << 16); }
__device__ __forceinline__ float bfhi(uint32_t u)  { return __uint_as_float(u & 0xffff0000u); }
__device__ __forceinline__ uint16_t f2bf(float f) {
  uint32_t u = __float_as_uint(f);
  u += 0x7fffu + ((u >> 16) & 1u);   // RNE
  return (uint16_t)(u >> 16);
}

// Detect whether float-tensor inputs are stored as bf16 (flag=1) or fp32 (flag=0).
// Reads first 256 words of `input` (N(0,1) data): if bf16, both 16-bit halves
// decode to |x| < 64 always; if fp32, the low half is mantissa garbage (~48%
// chance |x|>64 per word). P(misdetect) ~ 1e-73.
__global__ void k_detect(const uint32_t* __restrict__ w, int* __restrict__ flag) {
  if (threadIdx.x == 0 && blockIdx.x == 0) {
    int bad = 0;
    for (int i = 0; i < 256; i++) {
      float lo = bflo(w[i]);
      if (!(fabsf(lo) < 64.f)) bad++;     // NaN/inf/huge => not bf16 data
    }
    *flag = (bad == 0) ? 1 : 0;
  }
}

// dst fp32 <- src (bf16 or fp32 per flag)
__global__ void k_convert(const void* __restrict__ src, float* __restrict__ dst,
                          int n, const int* __restrict__ flag) {
  int i = blockIdx.x * 256 + threadIdx.x;
  if (i >= n) return;
  if (*flag) dst[i] = bf2f(((const uint16_t*)src)[i]);
  else       dst[i] = ((const float*)src)[i];
}

// out[c*R + r] = (float) in[elem_off + r*C + c]  ; R,C multiples of 32
__global__ void k_transpose(const void* __restrict__ in, int elem_off,
                            float* __restrict__ out, int R, int C,
                            const int* __restrict__ flag) {
  __shared__ float tile[32][33];
  int isbf = *flag;
  int c0 = blockIdx.x * 32, r0 = blockIdx.y * 32;
  int tx = threadIdx.x, ty = threadIdx.y;   // 32 x 8
  const uint16_t* u = (const uint16_t*)in;
  const float*    f = (const float*)in;
  #pragma unroll
  for (int dy = 0; dy < 32; dy += 8) {
    size_t idx = (size_t)elem_off + (size_t)(r0 + ty + dy) * C + (c0 + tx);
    tile[ty + dy][tx] = isbf ? bf2f(u[idx]) : f[idx];
  }
  __syncthreads();
  #pragma unroll
  for (int dy = 0; dy < 32; dy += 8)
    out[(size_t)(c0 + ty + dy) * R + (r0 + tx)] = tile[tx][ty + dy];
}

// hi = input@Wi + pre_b ; hj = input@Wj   (one block per node, 128 threads)
__global__ __launch_bounds__(128) void k1_hihj(
    const float* __restrict__ in_f, const float* __restrict__ prebF,
    const float* __restrict__ wiT, const float* __restrict__ wjT,
    float* __restrict__ hi, float* __restrict__ hj) {
  int bi = blockIdx.x, k = threadIdx.x;
  __shared__ float in_s[DIN];
  in_s[k] = in_f[(size_t)bi * DIN + k];
  __syncthreads();
  const float4* wi4 = (const float4*)&wiT[(size_t)k * DIN];
  const float4* wj4 = (const float4*)&wjT[(size_t)k * DIN];
  float a = prebF[k], b = 0.f;
  #pragma unroll 8
  for (int c = 0; c < DIN / 4; c++) {
    float4 wi = wi4[c], wj = wj4[c];
    float4 x  = *(const float4*)&in_s[c * 4];
    a += x.x * wi.x + x.y * wi.y + x.z * wi.z + x.w * wi.w;
    b += x.x * wj.x + x.y * wj.y + x.z * wj.z + x.w * wj.w;
  }
  hi[(size_t)bi * DIN + k] = a;
  hj[(size_t)bi * DIN + k] = b;
}

// Edge aggregation: per node, iterate edges, compute h_mod on the fly, reduce.
__global__ __launch_bounds__(128) void k2_agg(
    const void* __restrict__ adj_raw, const void* __restrict__ af_raw,
    const float* __restrict__ hi, const float* __restrict__ hj,
    const float* __restrict__ weT, float* __restrict__ m_ext,
    const int* __restrict__ flag) {
  int bi = blockIdx.x, k = threadIdx.x;           // 128 threads
  int isbf = *flag;
  __shared__ int s_cnt;
  __shared__ int nbr[Nn];
  if (k == 0) s_cnt = 0;
  __syncthreads();
  {
    size_t ao = (size_t)bi * Nn;
    float a0, a1;
    if (isbf) {
      a0 = bf2f(((const uint16_t*)adj_raw)[ao + k]);
      a1 = bf2f(((const uint16_t*)adj_raw)[ao + k + 128]);
    } else {
      a0 = ((const float*)adj_raw)[ao + k];
      a1 = ((const float*)adj_raw)[ao + k + 128];
    }
    if (a0 > 0.f) nbr[atomicAdd(&s_cnt, 1)] = k;
    if (a1 > 0.f) nbr[atomicAdd(&s_cnt, 1)] = k + 128;
  }
  __syncthreads();
  int cnt = s_cnt;

  float wreg[DE];                                  // We column k in registers
  const float4* wp = (const float4*)&weT[(size_t)k * DE];
  #pragma unroll
  for (int c = 0; c < DE / 4; c++) {
    float4 v = wp[c];
    wreg[4*c] = v.x; wreg[4*c+1] = v.y; wreg[4*c+2] = v.z; wreg[4*c+3] = v.w;
  }
  float base = hi[(size_t)bi * DIN + k];           // includes pre_b
  const float* hjb = &hj[(size_t)(bi & ~(Nn - 1)) * DIN];

  float s1 = 0.f, s2 = 0.f, mx = -1e30f, mn = 1e30f;
  if (isbf) {
    const uint16_t* af = (const uint16_t*)af_raw;
    for (int t = 0; t < cnt; t++) {
      int j = nbr[t];
      float hjv = hjb[(size_t)j * DIN + k];
      const uint4* efp = (const uint4*)&af[((size_t)bi * Nn + j) * DE];
      float dot = 0.f;
      #pragma unroll
      for (int c = 0; c < 8; c++) {
        uint4 v = efp[c];
        dot += bflo(v.x) * wreg[8*c+0]; dot += bfhi(v.x) * wreg[8*c+1];
        dot += bflo(v.y) * wreg[8*c+2]; dot += bfhi(v.y) * wreg[8*c+3];
        dot += bflo(v.z) * wreg[8*c+4]; dot += bfhi(v.z) * wreg[8*c+5];
        dot += bflo(v.w) * wreg[8*c+6]; dot += bfhi(v.w) * wreg[8*c+7];
      }
      float h = base + hjv + dot;
      s1 += h; s2 += h * h; mx = fmaxf(mx, h); mn = fminf(mn, h);
    }
  } else {
    const float* af = (const float*)af_raw;
    for (int t = 0; t < cnt; t++) {
      int j = nbr[t];
      float hjv = hjb[(size_t)j * DIN + k];
      const float4* efp = (const float4*)&af[((size_t)bi * Nn + j) * DE];
      float dot = 0.f;
      #pragma unroll
      for (int c = 0; c < 16; c++) {
        float4 v = efp[c];
        dot += v.x * wreg[4*c+0] + v.y * wreg[4*c+1]
             + v.z * wreg[4*c+2] + v.w * wreg[4*c+3];
      }
      float h = base + hjv + dot;
      s1 += h; s2 += h * h; mx = fmaxf(mx, h); mn = fminf(mn, h);
    }
  }

  float deg  = (float)cnt;
  float degc = fmaxf(deg, EPSF);
  float mean = s1 / degc;
  float var  = fmaxf(s2 / degc - mean * mean, 0.f);
  float stdv = sqrtf(var + EPSF);
  if (cnt == 0) { mx = 0.f; mn = 0.f; }
  float slog = logf(deg + 1.f) / AVGD;
  float inv  = 1.f / (slog + EPSF);

  float* mo = &m_ext[(size_t)bi * MEXT];
  mo[0*128+k] = mean;        mo[1*128+k] = mx;        mo[2*128+k] = mn;        mo[3*128+k]  = stdv;
  mo[4*128+k] = mean * slog; mo[5*128+k] = mx * slog; mo[6*128+k] = mn * slog; mo[7*128+k]  = stdv * slog;
  mo[8*128+k] = mean * inv;  mo[9*128+k] = mx * inv;  mo[10*128+k] = mn * inv; mo[11*128+k] = stdv * inv;
}

// Fused: y1 = [input|m_ext]@post_W + post_b ; y2 = leaky(y1@mix_W + mix_b) ; GRU
__global__ __launch_bounds__(256) void k3_post(
    const float* __restrict__ in_f, const float* __restrict__ m_ext,
    const float* __restrict__ postT, const float* __restrict__ pbF,
    const float* __restrict__ mixT,  const float* __restrict__ mbF,
    const float* __restrict__ WihF, const float* __restrict__ WhhF,
    const float* __restrict__ hid_f, void* __restrict__ out,
    const int* __restrict__ flag) {
  constexpr int NT = 8;
  __shared__ float A_s[NT * CT];     // 52 KB
  __shared__ float y_s[NT * Hn];
  __shared__ float x_s[NT * Hn];
  __shared__ float hid_s[NT * Hn];
  int tid = threadIdx.x;
  int n0  = blockIdx.x * NT;
  int isbf = *flag;

  for (int t = tid; t < NT * DIN; t += 256) {
    int n = t >> 7, c = t & 127;
    A_s[n * CT + c] = in_f[(size_t)(n0 + n) * DIN + c];
    hid_s[t]        = hid_f[(size_t)(n0 + n) * Hn + c];
  }
  for (int n = 0; n < NT; n++)
    for (int c = tid; c < MEXT; c += 256)
      A_s[n * CT + DIN + c] = m_ext[(size_t)(n0 + n) * MEXT + c];
  __syncthreads();

  int h = tid & 127, g = tid >> 7;   // g in {0,1}: 4 nodes each
  // ---- post GEMM ----
  float acc[4];
  float pb = pbF[h];
  acc[0] = acc[1] = acc[2] = acc[3] = pb;
  const float* wr = &postT[(size_t)h * CT];
  for (int c = 0; c < CT; c += 4) {
    float4 w = *(const float4*)&wr[c];
    #pragma unroll
    for (int u = 0; u < 4; u++) {
      float4 a = *(const float4*)&A_s[(g * 4 + u) * CT + c];
      acc[u] += a.x * w.x + a.y * w.y + a.z * w.z + a.w * w.w;
    }
  }
  #pragma unroll
  for (int u = 0; u < 4; u++) y_s[(g * 4 + u) * Hn + h] = acc[u];
  __syncthreads();

  // ---- mix + leaky ----
  float mb = mbF[h];
  float acc2[4]; acc2[0] = acc2[1] = acc2[2] = acc2[3] = mb;
  const float* mr = &mixT[(size_t)h * Hn];
  for (int c = 0; c < Hn; c += 4) {
    float4 w = *(const float4*)&mr[c];
    #pragma unroll
    for (int u = 0; u < 4; u++) {
      float4 a = *(const float4*)&y_s[(g * 4 + u) * Hn + c];
      acc2[u] += a.x * w.x + a.y * w.y + a.z * w.z + a.w * w.w;
    }
  }
  #pragma unroll
  for (int u = 0; u < 4; u++) {
    float v = acc2[u];
    x_s[(g * 4 + u) * Hn + h] = v > 0.f ? v : LEAKF * v;
  }
  __syncthreads();

  // ---- GRU ----
  float gi[3][4], gh[3][4];
  #pragma unroll
  for (int q = 0; q < 3; q++) {
    float giq[4] = {0.f, 0.f, 0.f, 0.f}, ghq[4] = {0.f, 0.f, 0.f, 0.f};
    const float4* wi = (const float4*)&WihF[(size_t)(q * Hn + h) * Hn];
    const float4* wh = (const float4*)&WhhF[(size_t)(q * Hn + h) * Hn];
    for (int c = 0; c < Hn / 4; c++) {
      float4 vi = wi[c], vh = wh[c];
      #pragma unroll
      for (int u = 0; u < 4; u++) {
        const float* xr = &x_s[(g * 4 + u) * Hn + c * 4];
        const float* hr = &hid_s[(g * 4 + u) * Hn + c * 4];
        giq[u] += xr[0] * vi.x + xr[1] * vi.y + xr[2] * vi.z + xr[3] * vi.w;
        ghq[u] += hr[0] * vh.x + hr[1] * vh.y + hr[2] * vh.z + hr[3] * vh.w;
      }
    }
    #pragma unroll
    for (int u = 0; u < 4; u++) { gi[q][u] = giq[u]; gh[q][u] = ghq[u]; }
  }
  #pragma unroll
  for (int u = 0; u < 4; u++) {
    int n = g * 4 + u;
    float r  = 1.f / (1.f + expf(-(gi[0][u] + gh[0][u])));
    float z  = 1.f / (1.f + expf(-(gi[1][u] + gh[1][u])));
    float nn = tanhf(gi[2][u] + r * gh[2][u]);
    float hv = hid_s[n * Hn + h];
    float res = (1.f - z) * nn + z * hv;
    size_t oidx = (size_t)(n0 + n) * Hn + h;
    if (isbf) ((uint16_t*)out)[oidx] = f2bf(res);
    else      ((float*)out)[oidx]    = res;
  }
}

extern "C" void kernel_launch(void* const* d_in, const int* in_sizes, int n_in,
                              void* d_out, int out_size, void* d_ws, size_t ws_size,
                              hipStream_t stream) {
  const void* input  = d_in[0];
  const void* adj    = d_in[1];
  const void* af     = d_in[2];
  const void* hidden = d_in[3];
  const void* pre_W  = d_in[4];
  const void* pre_b  = d_in[5];
  const void* post_W = d_in[6];
  const void* post_b = d_in[7];
  const void* mix_W  = d_in[8];
  const void* mix_b  = d_in[9];
  const void* Wih    = d_in[10];
  const void* Whh    = d_in[11];

  float* ws    = (float*)d_ws;
  float* hi    = ws;                   // 262144
  float* hj    = ws + 262144;          // 262144
  float* m_ext = ws + 524288;          // 3145728
  float* wiT   = ws + 3670016;         // 16384
  float* wjT   = ws + 3686400;         // 16384
  float* weT   = ws + 3702784;         // 8192
  float* postT = ws + 3710976;         // 212992
  float* mixT  = ws + 3923968;         // 16384
  float* in_f  = ws + 3940352;         // 262144
  float* hid_f = ws + 4202496;         // 262144
  float* WihF  = ws + 4464640;         // 49152
  float* WhhF  = ws + 4513792;         // 49152
  float* prebF = ws + 4562944;         // 128
  float* pbF   = ws + 4563072;         // 128
  float* mbF   = ws + 4563200;         // 128
  int*   flag  = (int*)(ws + 4563328);

  k_detect<<<1, 64, 0, stream>>>((const uint32_t*)input, flag);

  k_convert<<<1024, 256, 0, stream>>>(input,  in_f,  262144, flag);
  k_convert<<<1024, 256, 0, stream>>>(hidden, hid_f, 262144, flag);
  k_convert<<<192,  256, 0, stream>>>(Wih,    WihF,  49152,  flag);
  k_convert<<<192,  256, 0, stream>>>(Whh,    WhhF,  49152,  flag);
  k_convert<<<1,    256, 0, stream>>>(pre_b,  prebF, 128,    flag);
  k_convert<<<1,    256, 0, stream>>>(post_b, pbF,   128,    flag);
  k_convert<<<1,    256, 0, stream>>>(mix_b,  mbF,   128,    flag);

  dim3 tb(32, 8);
  k_transpose<<<dim3(4, 4),  tb, 0, stream>>>(pre_W, 0,         wiT,  128,  128, flag);
  k_transpose<<<dim3(4, 4),  tb, 0, stream>>>(pre_W, 128 * 128, wjT,  128,  128, flag);
  k_transpose<<<dim3(4, 2),  tb, 0, stream>>>(pre_W, 256 * 128, weT,  64,   128, flag);
  k_transpose<<<dim3(4, 52), tb, 0, stream>>>(post_W, 0,        postT, 1664, 128, flag);
  k_transpose<<<dim3(4, 4),  tb, 0, stream>>>(mix_W, 0,         mixT, 128,  128, flag);

  k1_hihj<<<BN, 128, 0, stream>>>(in_f, prebF, wiT, wjT, hi, hj);
  k2_agg<<<BN, 128, 0, stream>>>(adj, af, hi, hj, weT, m_ext, flag);
  k3_post<<<BN / 8, 256, 0, stream>>>(in_f, m_ext, postT, pbF, mixT, mbF,
                                      WihF, WhhF, hid_f, d_out, flag);
}

// Round 3
// 322.950 us; speedup vs baseline: 1.2299x; 1.2299x over previous
//
#include <hip/hip_runtime.h>
#include <cstdint>
#include <cstddef>

#define EPSF 1e-5f
#define LEAKF 0.01f
#define AVGD 3.3f

static constexpr int Nn = 256, DIN = 128, DE = 64, Hn = 128;
static constexpr int BN = 2048;            // nodes
static constexpr int CT = 1664;            // [input(128) | m_ext(1536)]

typedef short bf16x8 __attribute__((ext_vector_type(8)));
typedef float f32x4  __attribute__((ext_vector_type(4)));

__device__ __forceinline__ float bf2f(uint16_t u) { return __uint_as_float(((uint32_t)u) << 16); }
__device__ __forceinline__ float bflo(uint32_t u)  { return __uint_as_float(u << 16); }
__device__ __forceinline__ float bfhi(uint32_t u)  { return __uint_as_float(u & 0xffff0000u); }
__device__ __forceinline__ uint16_t f2bf(float f) {
  uint32_t u = __float_as_uint(f);
  u += 0x7fffu + ((u >> 16) & 1u);   // RNE
  return (uint16_t)(u >> 16);
}

// Per-block inline dtype probe: read input[lane&63] as a packed word; if data
// is bf16, both halves decode small. fp32 data: low half is mantissa garbage.
// Wave-uniform result; identical across waves/blocks. P(misdetect) ~ 1e-18.
__device__ __forceinline__ int detect_bf16(const uint32_t* w) {
  float lo = bflo(w[threadIdx.x & 63]);
  unsigned long long ok = __ballot(fabsf(lo) < 64.f);
  return ok == 0xFFFFFFFFFFFFFFFFull;
}
__device__ __forceinline__ float loadf(const void* p, size_t i, int isbf) {
  return isbf ? bf2f(((const uint16_t*)p)[i]) : ((const float*)p)[i];
}

__device__ __forceinline__ f32x4 mfma16(bf16x8 a, bf16x8 b, f32x4 c) {
  return __builtin_amdgcn_mfma_f32_16x16x32_bf16(a, b, c, 0, 0, 0);
}

// ---------------- prep: all weight reformatting in ONE dispatch ----------------
// blocks 0..15   : wiT  (fp32 transpose of pre_W[0:128])
// blocks 16..31  : wjT  (fp32 transpose of pre_W[128:256])
// blocks 32..39  : weT  (fp32 transpose of pre_W[256:320])
// blocks 40..247 : postTb (bf16 col-major transpose of post_W, 1664x128)
// blocks 248..263: mixTb  (bf16 col-major transpose of mix_W)
// blocks 264..287: Wihb (bf16 copy/convert)
// blocks 288..311: Whhb (bf16 copy/convert)
// blocks 312..439: Ab[:, 0:128] = bf16(input)
__global__ __launch_bounds__(256) void k_prep(
    const void* __restrict__ input, const void* __restrict__ pre_W,
    const void* __restrict__ post_W, const void* __restrict__ mix_W,
    const void* __restrict__ Wih, const void* __restrict__ Whh,
    float* __restrict__ wiT, float* __restrict__ wjT, float* __restrict__ weT,
    uint16_t* __restrict__ postTb, uint16_t* __restrict__ mixTb,
    uint16_t* __restrict__ Wihb, uint16_t* __restrict__ Whhb,
    uint16_t* __restrict__ Ab) {
  int isbf = detect_bf16((const uint32_t*)input);
  int b = blockIdx.x, tid = threadIdx.x;
  if (b < 264) {   // transposes
    __shared__ float tile[32][33];
    const void* src; int off, R, C, t; float* fdst = nullptr; uint16_t* bdst = nullptr;
    if (b < 16)       { src = pre_W;  off = 0;     fdst = wiT;    R = 128;  C = 128; t = b; }
    else if (b < 32)  { src = pre_W;  off = 16384; fdst = wjT;    R = 128;  C = 128; t = b - 16; }
    else if (b < 40)  { src = pre_W;  off = 32768; fdst = weT;    R = 64;   C = 128; t = b - 32; }
    else if (b < 248) { src = post_W; off = 0;     bdst = postTb; R = 1664; C = 128; t = b - 40; }
    else              { src = mix_W;  off = 0;     bdst = mixTb;  R = 128;  C = 128; t = b - 248; }
    int bx = t & 3, by = t >> 2;
    int tx = tid & 31, ty = tid >> 5;          // 32 x 8
    int c0 = bx * 32, r0 = by * 32;
    #pragma unroll
    for (int dy = 0; dy < 32; dy += 8) {
      size_t idx = (size_t)off + (size_t)(r0 + ty + dy) * C + (c0 + tx);
      tile[ty + dy][tx] = loadf(src, idx, isbf);
    }
    __syncthreads();
    #pragma unroll
    for (int dy = 0; dy < 32; dy += 8) {
      size_t o = (size_t)(c0 + ty + dy) * R + (r0 + tx);
      float v = tile[tx][ty + dy];
      if (fdst) fdst[o] = v; else bdst[o] = f2bf(v);
    }
  } else if (b < 312) {   // GRU weight bf16 copies
    const void* src = (b < 288) ? Wih : Whh;
    uint16_t* dst = (b < 288) ? Wihb : Whhb;
    int base = ((b < 288) ? (b - 264) : (b - 288)) * 2048 + tid * 8;
    uint16_t v[8];
    if (isbf) *(uint4*)v = *(const uint4*)((const uint16_t*)src + base);
    else { const float* s = (const float*)src + base;
           #pragma unroll
           for (int e = 0; e < 8; e++) v[e] = f2bf(s[e]); }
    *(uint4*)(dst + base) = *(uint4*)v;
  } else {                // Ab input columns
    int base = (b - 312) * 2048 + tid * 8;
    int node = base >> 7, col = base & 127;
    uint16_t v[8];
    if (isbf) *(uint4*)v = *(const uint4*)((const uint16_t*)input + base);
    else { const float* s = (const float*)input + base;
           #pragma unroll
           for (int e = 0; e < 8; e++) v[e] = f2bf(s[e]); }
    *(uint4*)(Ab + (size_t)node * CT + col) = *(uint4*)v;
  }
}

// ---------------- k1: hi = input@Wi + pre_b ; hj = input@Wj ----------------
__global__ __launch_bounds__(128) void k1_hihj(
    const void* __restrict__ input, const void* __restrict__ pre_b,
    const float* __restrict__ wiT, const float* __restrict__ wjT,
    float* __restrict__ hi, float* __restrict__ hj) {
  int isbf = detect_bf16((const uint32_t*)input);
  int bi = blockIdx.x, k = threadIdx.x;
  __shared__ float in_s[DIN];
  in_s[k] = loadf(input, (size_t)bi * DIN + k, isbf);
  __syncthreads();
  const float4* wi4 = (const float4*)&wiT[(size_t)k * DIN];
  const float4* wj4 = (const float4*)&wjT[(size_t)k * DIN];
  float a = loadf(pre_b, k, isbf), bacc = 0.f;
  #pragma unroll 8
  for (int c = 0; c < DIN / 4; c++) {
    float4 wi = wi4[c], wj = wj4[c];
    float4 x  = *(const float4*)&in_s[c * 4];
    a    += x.x * wi.x + x.y * wi.y + x.z * wi.z + x.w * wi.w;
    bacc += x.x * wj.x + x.y * wj.y + x.z * wj.z + x.w * wj.w;
  }
  hi[(size_t)bi * DIN + k] = a;
  hj[(size_t)bi * DIN + k] = bacc;
}

// ---------------- k2: edge aggregation -> Ab[:, 128:1664] (bf16) ----------------
__global__ __launch_bounds__(128) void k2_agg(
    const void* __restrict__ input, const void* __restrict__ adj_raw,
    const void* __restrict__ af_raw,
    const float* __restrict__ hi, const float* __restrict__ hj,
    const float* __restrict__ weT, uint16_t* __restrict__ Ab) {
  int isbf = detect_bf16((const uint32_t*)input);
  int bi = blockIdx.x, k = threadIdx.x;
  __shared__ int s_cnt;
  __shared__ int nbr[Nn];
  if (k == 0) s_cnt = 0;
  __syncthreads();
  {
    size_t ao = (size_t)bi * Nn;
    float a0 = loadf(adj_raw, ao + k, isbf);
    float a1 = loadf(adj_raw, ao + k + 128, isbf);
    if (a0 > 0.f) nbr[atomicAdd(&s_cnt, 1)] = k;
    if (a1 > 0.f) nbr[atomicAdd(&s_cnt, 1)] = k + 128;
  }
  __syncthreads();
  int cnt = s_cnt;

  float wreg[DE];
  const float4* wp = (const float4*)&weT[(size_t)k * DE];
  #pragma unroll
  for (int c = 0; c < DE / 4; c++) {
    float4 v = wp[c];
    wreg[4*c] = v.x; wreg[4*c+1] = v.y; wreg[4*c+2] = v.z; wreg[4*c+3] = v.w;
  }
  float base = hi[(size_t)bi * DIN + k];
  const float* hjb = &hj[(size_t)(bi & ~(Nn - 1)) * DIN];

  float s1 = 0.f, s2 = 0.f, mx = -1e30f, mn = 1e30f;
  if (isbf) {
    const uint16_t* af = (const uint16_t*)af_raw;
    for (int t = 0; t < cnt; t++) {
      int j = nbr[t];
      float hjv = hjb[(size_t)j * DIN + k];
      const uint4* efp = (const uint4*)&af[((size_t)bi * Nn + j) * DE];
      float dot = 0.f;
      #pragma unroll
      for (int c = 0; c < 8; c++) {
        uint4 v = efp[c];
        dot += bflo(v.x) * wreg[8*c+0]; dot += bfhi(v.x) * wreg[8*c+1];
        dot += bflo(v.y) * wreg[8*c+2]; dot += bfhi(v.y) * wreg[8*c+3];
        dot += bflo(v.z) * wreg[8*c+4]; dot += bfhi(v.z) * wreg[8*c+5];
        dot += bflo(v.w) * wreg[8*c+6]; dot += bfhi(v.w) * wreg[8*c+7];
      }
      float h = base + hjv + dot;
      s1 += h; s2 += h * h; mx = fmaxf(mx, h); mn = fminf(mn, h);
    }
  } else {
    const float* af = (const float*)af_raw;
    for (int t = 0; t < cnt; t++) {
      int j = nbr[t];
      float hjv = hjb[(size_t)j * DIN + k];
      const float4* efp = (const float4*)&af[((size_t)bi * Nn + j) * DE];
      float dot = 0.f;
      #pragma unroll
      for (int c = 0; c < 16; c++) {
        float4 v = efp[c];
        dot += v.x * wreg[4*c+0] + v.y * wreg[4*c+1]
             + v.z * wreg[4*c+2] + v.w * wreg[4*c+3];
      }
      float h = base + hjv + dot;
      s1 += h; s2 += h * h; mx = fmaxf(mx, h); mn = fminf(mn, h);
    }
  }

  float deg  = (float)cnt;
  float degc = fmaxf(deg, EPSF);
  float mean = s1 / degc;
  float var  = fmaxf(s2 / degc - mean * mean, 0.f);
  float stdv = sqrtf(var + EPSF);
  if (cnt == 0) { mx = 0.f; mn = 0.f; }
  float slog = logf(deg + 1.f) / AVGD;
  float inv  = 1.f / (slog + EPSF);

  uint16_t* mo = Ab + (size_t)bi * CT + 128;
  mo[0*128+k]  = f2bf(mean);        mo[1*128+k]  = f2bf(mx);
  mo[2*128+k]  = f2bf(mn);          mo[3*128+k]  = f2bf(stdv);
  mo[4*128+k]  = f2bf(mean * slog); mo[5*128+k]  = f2bf(mx * slog);
  mo[6*128+k]  = f2bf(mn * slog);   mo[7*128+k]  = f2bf(stdv * slog);
  mo[8*128+k]  = f2bf(mean * inv);  mo[9*128+k]  = f2bf(mx * inv);
  mo[10*128+k] = f2bf(mn * inv);    mo[11*128+k] = f2bf(stdv * inv);
}

// ---------------- k3: MFMA chain: post GEMM -> mix+leaky -> GRU ----------------
// 128 blocks x 16 nodes, 256 threads (4 waves). Wave w owns cols [32w, 32w+32).
__global__ __launch_bounds__(256) void k3_mfma(
    const uint16_t* __restrict__ Ab, const uint16_t* __restrict__ postTb,
    const void* __restrict__ post_b, const uint16_t* __restrict__ mixTb,
    const void* __restrict__ mix_b, const uint16_t* __restrict__ Wihb,
    const uint16_t* __restrict__ Whhb, const void* __restrict__ hidden,
    const void* __restrict__ input_flag, void* __restrict__ out) {
  constexpr int SA = 1688;   // A_s row stride (bf16 elems): 16B-aligned, ~2-way banks
  constexpr int SY = 152;    // y/x/hid row stride
  __shared__ __align__(16) uint16_t A_s[16 * SA];    // 54016 B (reused for y_s/x_s)
  __shared__ __align__(16) uint16_t hid_s[16 * SY];  // 4864 B
  int isbf = detect_bf16((const uint32_t*)input_flag);
  int tid = threadIdx.x;
  int n0 = blockIdx.x * 16;

  // stage A rows (16 x 1664 bf16)
  for (int i = tid; i < 16 * 208; i += 256) {
    int row = i / 208, c = (i % 208) * 8;
    *(uint4*)&A_s[row * SA + c] = *(const uint4*)&Ab[(size_t)(n0 + row) * CT + c];
  }
  // stage hidden as bf16
  {
    int i = tid * 8;
    int row = i >> 7, col = i & 127;
    uint16_t v[8];
    if (isbf) *(uint4*)v = *(const uint4*)((const uint16_t*)hidden + (size_t)(n0 + row) * Hn + col);
    else { const float* s = (const float*)hidden + (size_t)(n0 + row) * Hn + col;
           #pragma unroll
           for (int e = 0; e < 8; e++) v[e] = f2bf(s[e]); }
    *(uint4*)&hid_s[row * SY + col] = *(uint4*)v;
  }
  __syncthreads();

  int lane = tid & 63, w = tid >> 6;
  int m16 = lane & 15, quad = lane >> 4;
  int ncol0 = w * 32 + m16, ncol1 = ncol0 + 16;

  // ---- post GEMM: K = 1664 = 52 x 32 ----
  f32x4 acc0 = {0.f, 0.f, 0.f, 0.f}, acc1 = acc0;
  const uint16_t* bp0 = &postTb[(size_t)ncol0 * CT + quad * 8];
  const uint16_t* bp1 = &postTb[(size_t)ncol1 * CT + quad * 8];
  const uint16_t* ap  = &A_s[m16 * SA + quad * 8];
  for (int kt = 0; kt < 52; kt++) {
    bf16x8 a  = *(const bf16x8*)(ap + kt * 32);
    bf16x8 b0 = *(const bf16x8*)(bp0 + kt * 32);
    bf16x8 b1 = *(const bf16x8*)(bp1 + kt * 32);
    acc0 = mfma16(a, b0, acc0);
    acc1 = mfma16(a, b1, acc1);
  }
  float pb0 = loadf(post_b, ncol0, isbf), pb1 = loadf(post_b, ncol1, isbf);
  uint16_t* y_s = A_s;                 // overlay: A_s is dead now
  uint16_t* x_s = A_s + 16 * SY;
  __syncthreads();                     // all waves done reading A_s
  #pragma unroll
  for (int r = 0; r < 4; r++) {
    int row = quad * 4 + r;
    y_s[row * SY + ncol0] = f2bf(acc0[r] + pb0);
    y_s[row * SY + ncol1] = f2bf(acc1[r] + pb1);
  }
  __syncthreads();

  // ---- mix + leaky: K = 128 ----
  f32x4 macc0 = {0.f, 0.f, 0.f, 0.f}, macc1 = macc0;
  const uint16_t* mb0 = &mixTb[(size_t)ncol0 * Hn + quad * 8];
  const uint16_t* mb1 = &mixTb[(size_t)ncol1 * Hn + quad * 8];
  const uint16_t* ya  = &y_s[m16 * SY + quad * 8];
  #pragma unroll
  for (int kt = 0; kt < 4; kt++) {
    bf16x8 a  = *(const bf16x8*)(ya + kt * 32);
    bf16x8 b0 = *(const bf16x8*)(mb0 + kt * 32);
    bf16x8 b1 = *(const bf16x8*)(mb1 + kt * 32);
    macc0 = mfma16(a, b0, macc0);
    macc1 = mfma16(a, b1, macc1);
  }
  float mbias0 = loadf(mix_b, ncol0, isbf), mbias1 = loadf(mix_b, ncol1, isbf);
  #pragma unroll
  for (int r = 0; r < 4; r++) {
    int row = quad * 4 + r;
    float v0 = macc0[r] + mbias0; v0 = v0 > 0.f ? v0 : LEAKF * v0;
    float v1 = macc1[r] + mbias1; v1 = v1 > 0.f ? v1 : LEAKF * v1;
    x_s[row * SY + ncol0] = f2bf(v0);
    x_s[row * SY + ncol1] = f2bf(v1);
  }
  __syncthreads();

  // ---- GRU: gi = x@Wih^T, gh = hid@Whh^T ; gates wave-local ----
  f32x4 gi[3][2], gh[3][2];
  #pragma unroll
  for (int q = 0; q < 3; q++)
    #pragma unroll
    for (int t = 0; t < 2; t++) { gi[q][t] = {0.f,0.f,0.f,0.f}; gh[q][t] = {0.f,0.f,0.f,0.f}; }
  const uint16_t* xa = &x_s[m16 * SY + quad * 8];
  const uint16_t* ha = &hid_s[m16 * SY + quad * 8];
  int h0 = ncol0, h1 = ncol1;
  #pragma unroll
  for (int kt = 0; kt < 4; kt++) {
    bf16x8 ax = *(const bf16x8*)(xa + kt * 32);
    bf16x8 ah = *(const bf16x8*)(ha + kt * 32);
    #pragma unroll
    for (int q = 0; q < 3; q++) {
      bf16x8 bi0 = *(const bf16x8*)&Wihb[(size_t)(q * Hn + h0) * Hn + kt * 32 + quad * 8];
      bf16x8 bi1 = *(const bf16x8*)&Wihb[(size_t)(q * Hn + h1) * Hn + kt * 32 + quad * 8];
      bf16x8 bh0 = *(const bf16x8*)&Whhb[(size_t)(q * Hn + h0) * Hn + kt * 32 + quad * 8];
      bf16x8 bh1 = *(const bf16x8*)&Whhb[(size_t)(q * Hn + h1) * Hn + kt * 32 + quad * 8];
      gi[q][0] = mfma16(ax, bi0, gi[q][0]);
      gi[q][1] = mfma16(ax, bi1, gi[q][1]);
      gh[q][0] = mfma16(ah, bh0, gh[q][0]);
      gh[q][1] = mfma16(ah, bh1, gh[q][1]);
    }
  }
  #pragma unroll
  for (int t = 0; t < 2; t++) {
    int col = (t == 0) ? h0 : h1;
    #pragma unroll
    for (int r = 0; r < 4; r++) {
      int row = quad * 4 + r;
      float rg = 1.f / (1.f + expf(-(gi[0][t][r] + gh[0][t][r])));
      float zg = 1.f / (1.f + expf(-(gi[1][t][r] + gh[1][t][r])));
      float ng = tanhf(gi[2][t][r] + rg * gh[2][t][r]);
      float hv = bf2f(hid_s[row * SY + col]);
      float res = (1.f - zg) * ng + zg * hv;
      size_t oi = (size_t)(n0 + row) * Hn + col;
      if (isbf) ((uint16_t*)out)[oi] = f2bf(res);
      else      ((float*)out)[oi]    = res;
    }
  }
}

extern "C" void kernel_launch(void* const* d_in, const int* in_sizes, int n_in,
                              void* d_out, int out_size, void* d_ws, size_t ws_size,
                              hipStream_t stream) {
  const void* input  = d_in[0];
  const void* adj    = d_in[1];
  const void* af     = d_in[2];
  const void* hidden = d_in[3];
  const void* pre_W  = d_in[4];
  const void* pre_b  = d_in[5];
  const void* post_W = d_in[6];
  const void* post_b = d_in[7];
  const void* mix_W  = d_in[8];
  const void* mix_b  = d_in[9];
  const void* Wih    = d_in[10];
  const void* Whh    = d_in[11];

  float* ws = (float*)d_ws;
  float* hi  = ws;                  // 262144
  float* hj  = hi  + 262144;        // 262144
  float* wiT = hj  + 262144;        // 16384
  float* wjT = wiT + 16384;         // 16384
  float* weT = wjT + 16384;         // 8192
  uint16_t* Ab     = (uint16_t*)(weT + 8192);   // 2048*1664
  uint16_t* postTb = Ab + (size_t)BN * CT;      // 128*1664
  uint16_t* mixTb  = postTb + 128 * 1664;       // 128*128
  uint16_t* Wihb   = mixTb + 16384;             // 49152
  uint16_t* Whhb   = Wihb + 49152;              // 49152

  k_prep<<<440, 256, 0, stream>>>(input, pre_W, post_W, mix_W, Wih, Whh,
                                  wiT, wjT, weT, postTb, mixTb, Wihb, Whhb, Ab);
  k1_hihj<<<BN, 128, 0, stream>>>(input, pre_b, wiT, wjT, hi, hj);
  k2_agg<<<BN, 128, 0, stream>>>(input, adj, af, hi, hj, weT, Ab);
  k3_mfma<<<BN / 16, 256, 0, stream>>>(Ab, postTb, post_b, mixTb, mix_b,
                                       Wihb, Whhb, hidden, input, d_out);
}

// Round 4
// 226.892 us; speedup vs baseline: 1.7506x; 1.4234x over previous
//
#include <hip/hip_runtime.h>
#include <cstdint>
#include <cstddef>

#define EPSF 1e-5f
#define LEAKF 0.01f
#define AVGD 3.3f

static constexpr int Nn = 256, DIN = 128, DE = 64, Hn = 128;
static constexpr int BN = 2048;            // nodes
static constexpr int CT = 1664;            // [input(128) | m_ext(1536)]

typedef short bf16x8 __attribute__((ext_vector_type(8)));
typedef float f32x4  __attribute__((ext_vector_type(4)));
union BF8 { bf16x8 v; uint16_t u[8]; };

__device__ __forceinline__ float bf2f(uint16_t u) { return __uint_as_float(((uint32_t)u) << 16); }
__device__ __forceinline__ float bflo(uint32_t u)  { return __uint_as_float(u << 16); }
__device__ __forceinline__ uint16_t f2bf(float f) {
  uint32_t u = __float_as_uint(f);
  u += 0x7fffu + ((u >> 16) & 1u);   // RNE
  return (uint16_t)(u >> 16);
}

// Per-block inline dtype probe (bf16 vs fp32 storage). Wave-uniform.
__device__ __forceinline__ int detect_bf16(const uint32_t* w) {
  float lo = bflo(w[threadIdx.x & 63]);
  unsigned long long ok = __ballot(fabsf(lo) < 64.f);
  return ok == 0xFFFFFFFFFFFFFFFFull;
}
__device__ __forceinline__ float loadf(const void* p, size_t i, int isbf) {
  return isbf ? bf2f(((const uint16_t*)p)[i]) : ((const float*)p)[i];
}
__device__ __forceinline__ f32x4 mfma16(bf16x8 a, bf16x8 b, f32x4 c) {
  return __builtin_amdgcn_mfma_f32_16x16x32_bf16(a, b, c, 0, 0, 0);
}

// ---------------- prep: all weight/input reformatting, ONE dispatch ----------------
// b 0..15   : mixTb  (bf16 col-major transpose of mix_W 128x128)
// b 16..23  : weT    (unused fp32 — kept minimal; retained slot for layout stability)
// b 24..231 : postTb (bf16 col-major transpose of post_W 1664x128)
// b 232..251: preWb  (bf16 copy of pre_W 320x128)
// b 252..275: Wihb   | b 276..299: Whhb   (bf16 copies 384x128)
// b 300..427: Ab[:,0:128] = bf16(input)
// b 428..555: hidb = bf16(hidden)
__global__ __launch_bounds__(256) void k_prep(
    const void* __restrict__ input, const void* __restrict__ pre_W,
    const void* __restrict__ post_W, const void* __restrict__ mix_W,
    const void* __restrict__ Wih, const void* __restrict__ Whh,
    const void* __restrict__ hidden,
    uint16_t* __restrict__ preWb, uint16_t* __restrict__ postTb,
    uint16_t* __restrict__ mixTb, uint16_t* __restrict__ Wihb,
    uint16_t* __restrict__ Whhb, uint16_t* __restrict__ hidb,
    uint16_t* __restrict__ Ab) {
  int isbf = detect_bf16((const uint32_t*)input);
  int b = blockIdx.x, tid = threadIdx.x;
  if (b < 232) {   // transposes (bf16 out)
    if (b >= 16 && b < 24) return;   // spare
    __shared__ float tile[32][33];
    const void* src; int off, R, C, t; uint16_t* bdst;
    if (b < 16)      { src = mix_W;  off = 0; bdst = mixTb;  R = 128;  C = 128; t = b; }
    else             { src = post_W; off = 0; bdst = postTb; R = 1664; C = 128; t = b - 24; }
    int bx = t & 3, by = t >> 2;
    int tx = tid & 31, ty = tid >> 5;          // 32 x 8
    int c0 = bx * 32, r0 = by * 32;
    #pragma unroll
    for (int dy = 0; dy < 32; dy += 8) {
      size_t idx = (size_t)off + (size_t)(r0 + ty + dy) * C + (c0 + tx);
      tile[ty + dy][tx] = loadf(src, idx, isbf);
    }
    __syncthreads();
    #pragma unroll
    for (int dy = 0; dy < 32; dy += 8)
      bdst[(size_t)(c0 + ty + dy) * R + (r0 + tx)] = f2bf(tile[tx][ty + dy]);
  } else if (b < 428 && b >= 300) {   // input -> Ab (strided rows)
    int idx = (b - 300) * 2048 + tid * 8;
    int node = idx >> 7, col = idx & 127;
    uint16_t v[8];
    if (isbf) *(uint4*)v = *(const uint4*)((const uint16_t*)input + idx);
    else { const float* s = (const float*)input + idx;
           #pragma unroll
           for (int e = 0; e < 8; e++) v[e] = f2bf(s[e]); }
    *(uint4*)(Ab + (size_t)node * CT + col) = *(uint4*)v;
  } else {         // plain bf16 copies
    const void* src; uint16_t* dst; int base;
    if (b < 252)      { src = pre_W;  dst = preWb; base = (b - 232) * 2048; }
    else if (b < 276) { src = Wih;    dst = Wihb;  base = (b - 252) * 2048; }
    else if (b < 300) { src = Whh;    dst = Whhb;  base = (b - 276) * 2048; }
    else              { src = hidden; dst = hidb;  base = (b - 428) * 2048; }
    int i = base + tid * 8;
    uint16_t v[8];
    if (isbf) *(uint4*)v = *(const uint4*)((const uint16_t*)src + i);
    else { const float* s = (const float*)src + i;
           #pragma unroll
           for (int e = 0; e < 8; e++) v[e] = f2bf(s[e]); }
    *(uint4*)(dst + i) = *(uint4*)v;
  }
}

// ---------------- k1: hi = input@Wi + pre_b ; hj = input@Wj (MFMA) ----------------
// 512 blocks x 4 waves; wave = one 16x16 tile of the 2048x256 {hi|hj} output.
__global__ __launch_bounds__(256) void k1_mfma(
    const uint16_t* __restrict__ Ab, const uint16_t* __restrict__ preWb,
    const void* __restrict__ pre_b, const void* __restrict__ input_flag,
    float* __restrict__ hi, float* __restrict__ hj) {
  int isbf = detect_bf16((const uint32_t*)input_flag);
  int tid = threadIdx.x;
  int lane = tid & 63, w = tid >> 6;
  int wg = blockIdx.x * 4 + w;              // 0..2047
  int rt = wg >> 4, nt = wg & 15;
  int ishj = nt >> 3, ct = nt & 7;
  int m16 = lane & 15, quad = lane >> 4;
  int col = ct * 16 + m16;
  const uint16_t* ap = Ab + (size_t)(rt * 16 + m16) * CT + quad * 8;
  int kbase = ishj ? 128 : 0;
  f32x4 acc = {0.f, 0.f, 0.f, 0.f};
  #pragma unroll
  for (int kt = 0; kt < 4; kt++) {
    bf16x8 a = *(const bf16x8*)(ap + kt * 32);
    BF8 bb;
    #pragma unroll
    for (int j = 0; j < 8; j++)
      bb.u[j] = preWb[(size_t)(kbase + kt * 32 + quad * 8 + j) * 128 + col];
    acc = mfma16(a, bb.v, acc);
  }
  float bias = ishj ? 0.f : loadf(pre_b, col, isbf);
  float* dst = ishj ? hj : hi;
  #pragma unroll
  for (int r = 0; r < 4; r++)
    dst[(size_t)(rt * 16 + quad * 4 + r) * 128 + col] = acc[r] + bias;
}

// ---------------- k2: edge aggregation via MFMA -> Ab[:, 128:1664] ----------------
// 1 block per node, 256 thr (4 waves). Chunks of 16 edges; wave w owns cols [32w,32w+32).
__global__ __launch_bounds__(256) void k2_mfma(
    const void* __restrict__ input, const void* __restrict__ adj_raw,
    const void* __restrict__ af_raw,
    const float* __restrict__ hi, const float* __restrict__ hj,
    const uint16_t* __restrict__ preWb, uint16_t* __restrict__ Ab) {
  __shared__ int s_cnt;
  __shared__ int nbr[Nn];
  __shared__ __align__(16) uint16_t A_lds[16 * 72];   // stride 72: 2-way banks (free)
  int isbf = detect_bf16((const uint32_t*)input);
  int bi = blockIdx.x, tid = threadIdx.x;
  if (tid == 0) s_cnt = 0;
  __syncthreads();
  {
    float a = loadf(adj_raw, (size_t)bi * Nn + tid, isbf);
    if (a > 0.f) nbr[atomicAdd(&s_cnt, 1)] = tid;
  }
  __syncthreads();
  int cnt = s_cnt;

  int lane = tid & 63, w = tid >> 6;
  int m16 = lane & 15, quad = lane >> 4;
  int col0 = w * 32 + m16, col1 = col0 + 16;

  // B fragments: We = preWb rows 256..319 (row-major = B[k][n] layout)
  BF8 b00, b01, b10, b11;   // [tile][kstep]
  #pragma unroll
  for (int j = 0; j < 8; j++) {
    int k0 = 256 + quad * 8 + j, k1 = k0 + 32;
    b00.u[j] = preWb[(size_t)k0 * 128 + col0];
    b01.u[j] = preWb[(size_t)k1 * 128 + col0];
    b10.u[j] = preWb[(size_t)k0 * 128 + col1];
    b11.u[j] = preWb[(size_t)k1 * 128 + col1];
  }
  float base0 = hi[(size_t)bi * 128 + col0];
  float base1 = hi[(size_t)bi * 128 + col1];
  const float* hjb = &hj[(size_t)(bi & ~(Nn - 1)) * 128];

  float s1a = 0.f, s2a = 0.f, mxa = -1e30f, mna = 1e30f;
  float s1b = 0.f, s2b = 0.f, mxb = -1e30f, mnb = 1e30f;

  for (int ce = 0; ce < cnt; ce += 16) {
    __syncthreads();                 // A_lds free from previous chunk
    if (tid < 128) {                 // stage 16 edge rows (clamped tail)
      int e = tid >> 3, seg = tid & 7;
      int ei = ce + e; if (ei >= cnt) ei = cnt - 1;
      int j = nbr[ei];
      uint16_t v[8];
      if (isbf)
        *(uint4*)v = *(const uint4*)((const uint16_t*)af_raw + ((size_t)bi * Nn + j) * DE + seg * 8);
      else {
        const float* s = (const float*)af_raw + ((size_t)bi * Nn + j) * DE + seg * 8;
        #pragma unroll
        for (int x = 0; x < 8; x++) v[x] = f2bf(s[x]);
      }
      *(uint4*)&A_lds[e * 72 + seg * 8] = *(uint4*)v;
    }
    __syncthreads();
    float hjv0[4], hjv1[4]; int vld[4];
    #pragma unroll
    for (int r = 0; r < 4; r++) {
      int e = ce + quad * 4 + r;
      vld[r] = (e < cnt);
      int j = nbr[vld[r] ? e : (cnt - 1)];
      hjv0[r] = hjb[(size_t)j * 128 + col0];
      hjv1[r] = hjb[(size_t)j * 128 + col1];
    }
    bf16x8 a0 = *(const bf16x8*)&A_lds[m16 * 72 + quad * 8];
    bf16x8 a1 = *(const bf16x8*)&A_lds[m16 * 72 + 32 + quad * 8];
    f32x4 C0 = {0.f,0.f,0.f,0.f}, C1 = C0;
    C0 = mfma16(a0, b00.v, C0); C0 = mfma16(a1, b01.v, C0);
    C1 = mfma16(a0, b10.v, C1); C1 = mfma16(a1, b11.v, C1);
    #pragma unroll
    for (int r = 0; r < 4; r++) {
      float h0 = base0 + hjv0[r] + C0[r];
      float h1 = base1 + hjv1[r] + C1[r];
      if (vld[r]) {
        s1a += h0; s2a += h0 * h0; mxa = fmaxf(mxa, h0); mna = fminf(mna, h0);
        s1b += h1; s2b += h1 * h1; mxb = fmaxf(mxb, h1); mnb = fminf(mnb, h1);
      }
    }
  }
  // cross-quad reduce: lanes {m16, +16, +32, +48} hold partials of the same col
  #pragma unroll
  for (int off = 16; off <= 32; off <<= 1) {
    s1a += __shfl_xor(s1a, off); s2a += __shfl_xor(s2a, off);
    mxa = fmaxf(mxa, __shfl_xor(mxa, off)); mna = fminf(mna, __shfl_xor(mna, off));
    s1b += __shfl_xor(s1b, off); s2b += __shfl_xor(s2b, off);
    mxb = fmaxf(mxb, __shfl_xor(mxb, off)); mnb = fminf(mnb, __shfl_xor(mnb, off));
  }
  if (quad == 0) {
    float deg = (float)cnt, degc = fmaxf(deg, EPSF);
    float slog = logf(deg + 1.f) / AVGD;
    float inv  = 1.f / (slog + EPSF);
    uint16_t* mo = Ab + (size_t)bi * CT + 128;
    #pragma unroll
    for (int t = 0; t < 2; t++) {
      float s1 = t ? s1b : s1a, s2 = t ? s2b : s2a;
      float mx = t ? mxb : mxa, mn = t ? mnb : mna;
      int col = t ? col1 : col0;
      float mean = s1 / degc;
      float var  = fmaxf(s2 / degc - mean * mean, 0.f);
      float stdv = sqrtf(var + EPSF);
      if (cnt == 0) { mx = 0.f; mn = 0.f; }
      mo[0*128+col]  = f2bf(mean);        mo[1*128+col]  = f2bf(mx);
      mo[2*128+col]  = f2bf(mn);          mo[3*128+col]  = f2bf(stdv);
      mo[4*128+col]  = f2bf(mean * slog); mo[5*128+col]  = f2bf(mx * slog);
      mo[6*128+col]  = f2bf(mn * slog);   mo[7*128+col]  = f2bf(stdv * slog);
      mo[8*128+col]  = f2bf(mean * inv);  mo[9*128+col]  = f2bf(mx * inv);
      mo[10*128+col] = f2bf(mn * inv);    mo[11*128+col] = f2bf(stdv * inv);
    }
  }
}

// ---------------- k3a: post GEMM y = [input|m]@post_W + post_b (MFMA) ----------------
// 256 blocks x 4 waves; wave = one 16x16 C-tile, K=1664, dual accumulator chains.
__global__ __launch_bounds__(256) void k3a(
    const uint16_t* __restrict__ Ab, const uint16_t* __restrict__ postTb,
    const void* __restrict__ post_b, const void* __restrict__ input_flag,
    uint16_t* __restrict__ yb) {
  int isbf = detect_bf16((const uint32_t*)input_flag);
  int tid = threadIdx.x;
  int lane = tid & 63, w = tid >> 6;
  int wg = blockIdx.x * 4 + w;              // 0..1023
  int rt = wg >> 3, ct = wg & 7;
  int m16 = lane & 15, quad = lane >> 4;
  const uint16_t* ap = Ab     + (size_t)(rt * 16 + m16) * CT + quad * 8;
  const uint16_t* bp = postTb + (size_t)(ct * 16 + m16) * CT + quad * 8;
  f32x4 acc0 = {0.f,0.f,0.f,0.f}, acc1 = acc0;
  #pragma unroll 4
  for (int kt = 0; kt < 52; kt += 2) {
    bf16x8 a0 = *(const bf16x8*)(ap + kt * 32);
    bf16x8 b0 = *(const bf16x8*)(bp + kt * 32);
    bf16x8 a1 = *(const bf16x8*)(ap + kt * 32 + 32);
    bf16x8 b1 = *(const bf16x8*)(bp + kt * 32 + 32);
    acc0 = mfma16(a0, b0, acc0);
    acc1 = mfma16(a1, b1, acc1);
  }
  int col = ct * 16 + m16;
  float pb = loadf(post_b, col, isbf);
  #pragma unroll
  for (int r = 0; r < 4; r++)
    yb[(size_t)(rt * 16 + quad * 4 + r) * 128 + col] = f2bf(acc0[r] + acc1[r] + pb);
}

// ---------------- k3b: mix+leaky -> GRU -> out (MFMA, fused) ----------------
// 128 blocks x 8 waves; block = 16 nodes; wave w owns col-tile w.
__global__ __launch_bounds__(512) void k3b(
    const uint16_t* __restrict__ yb, const uint16_t* __restrict__ mixTb,
    const void* __restrict__ mix_b, const uint16_t* __restrict__ Wihb,
    const uint16_t* __restrict__ Whhb, const uint16_t* __restrict__ hidb,
    const void* __restrict__ input_flag, void* __restrict__ out) {
  constexpr int SX = 136;
  __shared__ __align__(16) uint16_t x_s[16 * SX];
  __shared__ __align__(16) uint16_t hid_s[16 * SX];
  int isbf = detect_bf16((const uint32_t*)input_flag);
  int tid = threadIdx.x;
  int n0 = blockIdx.x * 16;
  if (tid < 256) {   // stage hidden (16 x 128 bf16)
    int row = tid >> 4, c = (tid & 15) * 8;
    *(uint4*)&hid_s[row * SX + c] = *(const uint4*)&hidb[(size_t)(n0 + row) * 128 + c];
  }
  int lane = tid & 63, w = tid >> 6;
  int m16 = lane & 15, quad = lane >> 4;
  int col = w * 16 + m16;

  // mix GEMM (A = y from global)
  f32x4 acc = {0.f,0.f,0.f,0.f};
  const uint16_t* ya = yb    + (size_t)(n0 + m16) * 128 + quad * 8;
  const uint16_t* mb = mixTb + (size_t)col * 128 + quad * 8;
  #pragma unroll
  for (int kt = 0; kt < 4; kt++)
    acc = mfma16(*(const bf16x8*)(ya + kt * 32), *(const bf16x8*)(mb + kt * 32), acc);
  float mbias = loadf(mix_b, col, isbf);
  __syncthreads();
  #pragma unroll
  for (int r = 0; r < 4; r++) {
    float v = acc[r] + mbias; v = v > 0.f ? v : LEAKF * v;
    x_s[(quad * 4 + r) * SX + col] = f2bf(v);
  }
  __syncthreads();

  // GRU
  f32x4 gi[3], gh[3];
  #pragma unroll
  for (int q = 0; q < 3; q++) { gi[q] = {0.f,0.f,0.f,0.f}; gh[q] = {0.f,0.f,0.f,0.f}; }
  const uint16_t* xa = &x_s[m16 * SX + quad * 8];
  const uint16_t* ha = &hid_s[m16 * SX + quad * 8];
  #pragma unroll
  for (int kt = 0; kt < 4; kt++) {
    bf16x8 ax = *(const bf16x8*)(xa + kt * 32);
    bf16x8 ah = *(const bf16x8*)(ha + kt * 32);
    #pragma unroll
    for (int q = 0; q < 3; q++) {
      bf16x8 bi = *(const bf16x8*)&Wihb[(size_t)(q * 128 + col) * 128 + kt * 32 + quad * 8];
      bf16x8 bh = *(const bf16x8*)&Whhb[(size_t)(q * 128 + col) * 128 + kt * 32 + quad * 8];
      gi[q] = mfma16(ax, bi, gi[q]);
      gh[q] = mfma16(ah, bh, gh[q]);
    }
  }
  #pragma unroll
  for (int r = 0; r < 4; r++) {
    int row = quad * 4 + r;
    float rg = 1.f / (1.f + expf(-(gi[0][r] + gh[0][r])));
    float zg = 1.f / (1.f + expf(-(gi[1][r] + gh[1][r])));
    float ng = tanhf(gi[2][r] + rg * gh[2][r]);
    float hv = bf2f(hid_s[row * SX + col]);
    float res = (1.f - zg) * ng + zg * hv;
    size_t oi = (size_t)(n0 + row) * 128 + col;
    if (isbf) ((uint16_t*)out)[oi] = f2bf(res);
    else      ((float*)out)[oi]    = res;
  }
}

extern "C" void kernel_launch(void* const* d_in, const int* in_sizes, int n_in,
                              void* d_out, int out_size, void* d_ws, size_t ws_size,
                              hipStream_t stream) {
  const void* input  = d_in[0];
  const void* adj    = d_in[1];
  const void* af     = d_in[2];
  const void* hidden = d_in[3];
  const void* pre_W  = d_in[4];
  const void* pre_b  = d_in[5];
  const void* post_W = d_in[6];
  const void* post_b = d_in[7];
  const void* mix_W  = d_in[8];
  const void* mix_b  = d_in[9];
  const void* Wih    = d_in[10];
  const void* Whh    = d_in[11];

  float* ws = (float*)d_ws;
  float* hi = ws;                         // 262144 f
  float* hj = hi + 262144;                // 262144 f
  uint16_t* Ab     = (uint16_t*)(hj + 262144);   // 2048*1664
  uint16_t* postTb = Ab + (size_t)BN * CT;       // 212992
  uint16_t* mixTb  = postTb + 212992;            // 16384
  uint16_t* preWb  = mixTb + 16384;              // 40960
  uint16_t* Wihb   = preWb + 40960;              // 49152
  uint16_t* Whhb   = Wihb + 49152;               // 49152
  uint16_t* hidb   = Whhb + 49152;               // 262144
  uint16_t* yb     = hidb + 262144;              // 262144

  k_prep<<<556, 256, 0, stream>>>(input, pre_W, post_W, mix_W, Wih, Whh, hidden,
                                  preWb, postTb, mixTb, Wihb, Whhb, hidb, Ab);
  k1_mfma<<<512, 256, 0, stream>>>(Ab, preWb, pre_b, input, hi, hj);
  k2_mfma<<<BN, 256, 0, stream>>>(input, adj, af, hi, hj, preWb, Ab);
  k3a<<<256, 256, 0, stream>>>(Ab, postTb, post_b, input, yb);
  k3b<<<128, 512, 0, stream>>>(yb, mixTb, mix_b, Wihb, Whhb, hidb, input, d_out);
}